// Round 4
// baseline (923.290 us; speedup 1.0000x reference)
//
#include <hip/hip_runtime.h>
#include <hip/hip_cooperative_groups.h>

namespace cg = cooperative_groups;

// DeepFM: B=16384, D=1024, L=4.
// Round 3: ONE cooperative kernel (prep + 5 GEMM layers, grid-synced).
//   Rationale: round-2 counters showed ~75us (24%) of wall time was
//   inter-dispatch launch overhead (6 dependent launches x ~12.5us); the
//   GEMM itself (44us, 781 TF) is at ~92% of the 8-phase K=1024 envelope.
//   grid = 64x4 = 256 blocks = 256 CUs, 128KiB LDS => exactly 1 block/CU.
//   Cross-XCD visibility: __threadfence() (agent-scope: buffer_wbl2 /
//   buffer_inv) on both sides of every grid sync.

#define DDIM 1024
#define BROWS 16384
#define NIT 8   // K / 128

typedef __attribute__((ext_vector_type(8))) short s8v;   // 8 bf16
typedef __attribute__((ext_vector_type(4))) float f4v;   // 4 fp32

__device__ __forceinline__ unsigned short f2bf(float f) {
    unsigned int u = __float_as_uint(f);
    u += 0x7fffu + ((u >> 16) & 1u);   // round-to-nearest-even
    return (unsigned short)(u >> 16);
}
__device__ __forceinline__ float bf2f(unsigned short u) {
    return __uint_as_float(((unsigned int)u) << 16);
}
__device__ __forceinline__ void gld16(const void* g, void* l) {
    __builtin_amdgcn_global_load_lds(
        (const __attribute__((address_space(1))) unsigned int*)g,
        (__attribute__((address_space(3))) unsigned int*)l, 16, 0, 0);
}

#define MF(a, b, c) __builtin_amdgcn_mfma_f32_16x16x32_bf16(a, b, c, 0, 0, 0)
#define BAR()   __builtin_amdgcn_s_barrier()
#define VMC(n)  asm volatile("s_waitcnt vmcnt(" #n ")" ::: "memory")

// byte offset within one 128x64-bf16 half-tile, with 16B-chunk XOR swizzle
#define SWOFF(lr, cc) ((lr) * 128 + ((((cc) ^ ((lr) & 7))) << 4))

#define SH(src, dst) {                                              \
    gld16((src) + soff,                   (char*)(dst) + t * 16);   \
    gld16((src) + soff + (size_t)64 * K,  (char*)(dst) + t * 16 + 8192); }

#define READ_A(P, m0) {                                                               \
    af[0][0] = *(const s8v*)((const char*)(P) + SWOFF((m0) * 16 + mrow,      quad));      \
    af[0][1] = *(const s8v*)((const char*)(P) + SWOFF((m0) * 16 + mrow,      4 + quad));  \
    af[1][0] = *(const s8v*)((const char*)(P) + SWOFF((m0) * 16 + 16 + mrow, quad));      \
    af[1][1] = *(const s8v*)((const char*)(P) + SWOFF((m0) * 16 + 16 + mrow, 4 + quad)); }

#define READ_B(P) {                                                                   \
    bfr[0][0] = *(const s8v*)((const char*)(P) + SWOFF(bl + mrow,      quad));            \
    bfr[0][1] = *(const s8v*)((const char*)(P) + SWOFF(bl + mrow,      4 + quad));        \
    bfr[1][0] = *(const s8v*)((const char*)(P) + SWOFF(bl + 16 + mrow, quad));            \
    bfr[1][1] = *(const s8v*)((const char*)(P) + SWOFF(bl + 16 + mrow, 4 + quad));        \
    bfr[2][0] = *(const s8v*)((const char*)(P) + SWOFF(bl + 32 + mrow, quad));            \
    bfr[2][1] = *(const s8v*)((const char*)(P) + SWOFF(bl + 32 + mrow, 4 + quad));        \
    bfr[3][0] = *(const s8v*)((const char*)(P) + SWOFF(bl + 48 + mrow, quad));            \
    bfr[3][1] = *(const s8v*)((const char*)(P) + SWOFF(bl + 48 + mrow, 4 + quad)); }

#define MMA8(m0, s) {                                              \
    acc[m0][0]       = MF(af[0][s], bfr[0][s], acc[m0][0]);        \
    acc[m0][1]       = MF(af[0][s], bfr[1][s], acc[m0][1]);        \
    acc[m0][2]       = MF(af[0][s], bfr[2][s], acc[m0][2]);        \
    acc[m0][3]       = MF(af[0][s], bfr[3][s], acc[m0][3]);        \
    acc[(m0) + 1][0] = MF(af[1][s], bfr[0][s], acc[(m0) + 1][0]);  \
    acc[(m0) + 1][1] = MF(af[1][s], bfr[1][s], acc[(m0) + 1][1]);  \
    acc[(m0) + 1][2] = MF(af[1][s], bfr[2][s], acc[(m0) + 1][2]);  \
    acc[(m0) + 1][3] = MF(af[1][s], bfr[3][s], acc[(m0) + 1][3]); }

#define MMA16(m0) { __builtin_amdgcn_s_setprio(1); MMA8(m0, 0) MMA8(m0, 1) \
                    __builtin_amdgcn_s_setprio(0); }

__global__ __launch_bounds__(512, 2) void deepfm_fused(
    const float* __restrict__ x,  const float* __restrict__ Ws,
    const float* __restrict__ bs, const float* __restrict__ Wo,
    const float* __restrict__ bo, float* __restrict__ out,
    unsigned short* __restrict__ xb, unsigned short* __restrict__ h0,
    unsigned short* __restrict__ h1, unsigned short* __restrict__ wb,
    float* __restrict__ rsm)
{
    constexpr int K = DDIM, N = DDIM;
    // [A=0/B=1][buf][half][128*64] bf16 = 128 KiB
    __shared__ unsigned short smem[2][2][2][128 * 64];

    cg::grid_group grid = cg::this_grid();

    const int t = threadIdx.x;            // 0..511
    const int lane = t & 63;
    const int wid  = t >> 6;              // 0..7
    const int wr   = wid >> 2;            // 0..1  (M half)
    const int wc   = wid & 3;             // 0..3  (N quarter)
    const int mrow = lane & 15;
    const int quad = lane >> 4;
    const int rowBase = blockIdx.x * 256; // bx in [0,64)
    const int colBase = blockIdx.y * 256; // by in [0,4)
    const int bid = blockIdx.x * 4 + blockIdx.y;   // 0..255

    // ================= phase 0: prep (x->bf16 + rowsum, weights->bf16) ====
    {
        const int rbase = bid * 64;
        #pragma unroll 1
        for (int g = 0; g < 8; ++g) {
            const int row = rbase + g * 8 + wid;       // one wave per row
            const float* xr = x + (size_t)row * DDIM;
            float s = 0.f;
            #pragma unroll
            for (int j = 0; j < 4; ++j) {
                const float4 v = *(const float4*)(xr + (j * 64 + lane) * 4);
                ushort4 o;
                o.x = f2bf(v.x); o.y = f2bf(v.y); o.z = f2bf(v.z); o.w = f2bf(v.w);
                *(ushort4*)(xb + (size_t)row * DDIM + (j * 64 + lane) * 4) = o;
                s += v.x + v.y + v.z + v.w;
            }
            #pragma unroll
            for (int off = 32; off > 0; off >>= 1) s += __shfl_down(s, off, 64);
            if (lane == 0) rsm[row] = s;
        }
        // weights: 5*1024*1024 fp32 = 1,310,720 float4; 5120/block, 10/thread
        #pragma unroll
        for (int j = 0; j < 10; ++j) {
            const int idx = bid * 5120 + j * 512 + t;
            const float4 v = (idx < 4 * 262144) ? ((const float4*)Ws)[idx]
                                                : ((const float4*)Wo)[idx - 4 * 262144];
            ushort4 o;
            o.x = f2bf(v.x); o.y = f2bf(v.y); o.z = f2bf(v.z); o.w = f2bf(v.w);
            ((ushort4*)wb)[idx] = o;
        }
    }
    __threadfence();   // release: flush this XCD's L2 (buffer_wbl2)
    grid.sync();
    __threadfence();   // acquire: invalidate this XCD's L2 (buffer_inv)

    // staging: thread t covers row t>>3 (+64 for 2nd load), 16B chunk t&7.
    // inverse-swizzled global source so linear LDS dest ends up swizzled.
    const int srow = t >> 3;
    const size_t soff = (size_t)srow * K + (size_t)(((t & 7) ^ (srow & 7)) * 8);

    unsigned short* const a00 = &smem[0][0][0][0];
    unsigned short* const a01 = &smem[0][0][1][0];
    unsigned short* const a10 = &smem[0][1][0][0];
    unsigned short* const a11 = &smem[0][1][1][0];
    unsigned short* const b00 = &smem[1][0][0][0];
    unsigned short* const b01 = &smem[1][0][1][0];
    unsigned short* const b10 = &smem[1][1][0][0];
    unsigned short* const b11 = &smem[1][1][1][0];

    const unsigned short* const aR0 = wr ? a01 : a00;       // buf0
    const unsigned short* const aR1 = wr ? a11 : a10;       // buf1
    const unsigned short* const bR0 = (wc >> 1) ? b01 : b00;
    const unsigned short* const bR1 = (wc >> 1) ? b11 : b10;
    const int bl = (wc & 1) * 64;

    // ================= 5 GEMM layers, grid-synced =========================
    #pragma unroll 1
    for (int l = 0; l < 5; ++l) {
        const unsigned short* Acur = (l == 0) ? xb : ((l & 1) ? h0 : h1);
        const unsigned short* Bwc  = wb + (size_t)l * DDIM * DDIM;
        const float* bias = (l == 4) ? bo : (bs + (size_t)l * DDIM);
        unsigned short* outb = (l & 1) ? h1 : h0;       // used for l < 4

        const unsigned short* const Ab0 = Acur + (size_t)rowBase * K;
        const unsigned short* const Ab1 = Ab0 + (size_t)128 * K;
        const unsigned short* const Bb0 = Bwc + (size_t)colBase * K;
        const unsigned short* const Bb1 = Bb0 + (size_t)128 * K;

        f4v acc[8][4] = {};
        s8v af[2][2], bfr[4][2];

        // ---- prologue: buf0 A+B, buf1 B; wait buf0, let buf1-B fly -------
        SH(Ab0,      a00); SH(Ab1,      a01);
        SH(Bb0,      b00); SH(Bb1,      b01);
        SH(Bb0 + 64, b10); SH(Bb1 + 64, b11);
        VMC(4);
        BAR();
        READ_B(bR0); READ_A(aR0, 0);          // ph1 frags

        #pragma unroll 1
        for (int it = 0; it < NIT; ++it) {
            const int ka = it * 128, kb = ka + 64;
            const bool more = it < NIT - 1;

            // ======== tile a = 2it (buf0), phases 1-4 ========
            SH(Ab0 + kb, a10);
            BAR(); MMA16(0); BAR();
            READ_A(aR0, 2);
            SH(Ab1 + kb, a11);
            BAR(); MMA16(2); BAR();
            READ_A(aR0, 4);
            if (more) SH(Bb0 + ka + 128, b00);
            BAR(); MMA16(4); BAR();
            READ_A(aR0, 6);
            if (more) SH(Bb1 + ka + 128, b01);
            if (more) { VMC(4); } else { VMC(0); }
            BAR();
            MMA16(6);
            READ_B(bR1); READ_A(aR1, 0);      // hoisted ph5 frags
            BAR();

            // ======== tile b = 2it+1 (buf1), phases 5-8 ========
            if (more) SH(Ab0 + ka + 128, a00);
            BAR(); MMA16(0); BAR();
            READ_A(aR1, 2);
            if (more) SH(Ab1 + ka + 128, a01);
            BAR(); MMA16(2); BAR();
            READ_A(aR1, 4);
            if (more) SH(Bb0 + kb + 128, b10);
            BAR(); MMA16(4); BAR();
            READ_A(aR1, 6);
            if (more) SH(Bb1 + kb + 128, b11);
            if (more) { VMC(4); }
            BAR();
            MMA16(6);
            if (more) { READ_B(bR0); READ_A(aR0, 0); }   // next-iter ph1
            BAR();
        }

        // ---- epilogue. C/D layout: col = lane&15, row = quad*4 + reg -----
        if (l == 4) {
            float* sCf = (float*)smem;                 // 128x256 fp32
            #pragma unroll 1
            for (int half = 0; half < 2; ++half) {
                __syncthreads();
                if (wr == half) {
                    #pragma unroll
                    for (int ni = 0; ni < 4; ++ni) {
                        const int n = wc * 64 + ni * 16 + mrow;
                        const float bv = bias[colBase + n];
                        #pragma unroll
                        for (int mi = 0; mi < 8; ++mi)
                            #pragma unroll
                            for (int r = 0; r < 4; ++r)
                                sCf[(mi * 16 + quad * 4 + r) * 256 + n] = acc[mi][ni][r] + bv;
                    }
                }
                __syncthreads();
                #pragma unroll
                for (int p = 0; p < 16; ++p) {
                    const int idx = t + p * 512;       // float4 chunk 0..8191
                    const int row = idx >> 6, ch = idx & 63;
                    const float4 v = ((const float4*)sCf)[idx];
                    *(float4*)(out + (size_t)(rowBase + half * 128 + row) * N + colBase + ch * 4) = v;
                }
            }
        } else {
            __syncthreads();
            unsigned short* sC = (unsigned short*)smem;  // 256x256 bf16
            #pragma unroll
            for (int ni = 0; ni < 4; ++ni) {
                const int n = wc * 64 + ni * 16 + mrow;
                const float bv = bias[colBase + n];
                #pragma unroll
                for (int mi = 0; mi < 8; ++mi)
                    #pragma unroll
                    for (int r = 0; r < 4; ++r) {
                        const int row = wr * 128 + mi * 16 + quad * 4 + r;
                        float v = acc[mi][ni][r] + bv;
                        v = v > 0.f ? v : 0.f;
                        sC[row * 256 + n] = f2bf(v);
                    }
            }
            __syncthreads();
            #pragma unroll
            for (int p = 0; p < 16; ++p) {
                const int idx = t + p * 512;             // ushort8 chunk
                const int row = idx >> 5, ch = idx & 31;
                s8v c = *(const s8v*)&sC[row * 256 + ch * 8];
                if (l == 3) {
                    const float rsv = rsm[rowBase + row];
                    const s8v xv = *(const s8v*)&xb[(size_t)(rowBase + row) * DDIM + colBase + ch * 8];
                    #pragma unroll
                    for (int j = 0; j < 8; ++j) {
                        float itv = bf2f((unsigned short)xv[j]) * rsv;
                        itv = itv > 0.f ? itv : 0.f;
                        c[j] = (short)f2bf(0.5f * (bf2f((unsigned short)c[j]) + itv));
                    }
                }
                *(s8v*)&outb[(size_t)(rowBase + row) * DDIM + colBase + ch * 8] = c;
            }
        }

        if (l < 4) {
            __threadfence();   // release (buffer_wbl2)
            grid.sync();
            __threadfence();   // acquire (buffer_inv)
        }
    }
}

extern "C" void kernel_launch(void* const* d_in, const int* in_sizes, int n_in,
                              void* d_out, int out_size, void* d_ws, size_t ws_size,
                              hipStream_t stream) {
    const float* x  = (const float*)d_in[0];
    const float* Ws = (const float*)d_in[1];
    const float* bs = (const float*)d_in[2];
    const float* Wo = (const float*)d_in[3];
    const float* bo = (const float*)d_in[4];
    float* out = (float*)d_out;

    char* ws = (char*)d_ws;
    unsigned short* xb  = (unsigned short*)(ws);                 // 32 MB bf16 x
    unsigned short* h0  = (unsigned short*)(ws + 33554432);      // 32 MB
    unsigned short* h1  = (unsigned short*)(ws + 67108864);      // 32 MB
    unsigned short* wb  = (unsigned short*)(ws + 100663296);     // 10 MB weights bf16
    float*          rsm = (float*)(ws + 111149056);              // 64 KB rowsum

    void* args[11] = {(void*)&x, (void*)&Ws, (void*)&bs, (void*)&Wo, (void*)&bo,
                      (void*)&out, (void*)&xb, (void*)&h0, (void*)&h1, (void*)&wb,
                      (void*)&rsm};
    hipLaunchCooperativeKernel(deepfm_fused, dim3(BROWS / 256, DDIM / 256),
                               dim3(512), args, 0u, stream);
}

// Round 5
// 415.186 us; speedup vs baseline: 2.2238x; 2.2238x over previous
//
#include <hip/hip_runtime.h>

// DeepFM: B=16384, D=1024, L=4.
// Round 5: XCD-LOCAL fused kernel. Round-4's cooperative version lost 570us
// to per-wave L2 writeback/invalidate (agent fences) + grid.sync. This
// version makes ALL inter-layer dataflow XCD-local:
//   block T = xcd*32 + slot owns tile (bx=T>>2, by=T&3); XCD x owns rows
//   [2048x, 2048x+2048) for every layer -> h producer/consumer share one L2.
//   Sync = per-XCD barrier (32 blocks, device atomicAdd + relaxed spin,
//   NO cache maintenance). L1 staleness on h re-read: SC0 (L1-bypass) on
//   A-staging global_load_lds. Weights converted in a separate tiny kernel
//   (cross-XCD consumers; kernel boundary = clean flush). 256x256 8-phase
//   GEMM schedule unchanged (proven 44us/layer).

#define DDIM 1024
#define BROWS 16384
#define NIT 8   // K / 128

typedef __attribute__((ext_vector_type(8))) short s8v;   // 8 bf16
typedef __attribute__((ext_vector_type(4))) float f4v;   // 4 fp32

__device__ __forceinline__ unsigned short f2bf(float f) {
    unsigned int u = __float_as_uint(f);
    u += 0x7fffu + ((u >> 16) & 1u);   // round-to-nearest-even
    return (unsigned short)(u >> 16);
}
__device__ __forceinline__ float bf2f(unsigned short u) {
    return __uint_as_float(((unsigned int)u) << 16);
}
__device__ __forceinline__ void gld16(const void* g, void* l) {
    __builtin_amdgcn_global_load_lds(
        (const __attribute__((address_space(1))) unsigned int*)g,
        (__attribute__((address_space(3))) unsigned int*)l, 16, 0, 0);
}
// SC0 (CPol bit0): agent-coherent load, bypasses L1 -> no stale h lines.
__device__ __forceinline__ void gld16c(const void* g, void* l) {
    __builtin_amdgcn_global_load_lds(
        (const __attribute__((address_space(1))) unsigned int*)g,
        (__attribute__((address_space(3))) unsigned int*)l, 16, 0, 1);
}

// -------- weight conversion: fp32 -> bf16 (cross-XCD consumers) ----------
__global__ __launch_bounds__(256) void prep_w(
    const float* __restrict__ Ws, const float* __restrict__ Wo,
    unsigned short* __restrict__ wb)
{
    #pragma unroll
    for (int j = 0; j < 4; ++j) {
        const int idx = blockIdx.x * 1024 + j * 256 + threadIdx.x;
        const float4 v = (idx < 4 * 262144) ? ((const float4*)Ws)[idx]
                                            : ((const float4*)Wo)[idx - 4 * 262144];
        ushort4 o;
        o.x = f2bf(v.x); o.y = f2bf(v.y); o.z = f2bf(v.z); o.w = f2bf(v.w);
        ((ushort4*)wb)[idx] = o;
    }
}

#define MF(a, b, c) __builtin_amdgcn_mfma_f32_16x16x32_bf16(a, b, c, 0, 0, 0)
#define BAR()   __builtin_amdgcn_s_barrier()
#define VMC(n)  asm volatile("s_waitcnt vmcnt(" #n ")" ::: "memory")

// byte offset within one 128x64-bf16 half-tile, with 16B-chunk XOR swizzle
#define SWOFF(lr, cc) ((lr) * 128 + ((((cc) ^ ((lr) & 7))) << 4))

#define SHA(src, dst) {                                              \
    gld16c((src) + soff,                   (char*)(dst) + t * 16);   \
    gld16c((src) + soff + (size_t)64 * K,  (char*)(dst) + t * 16 + 8192); }
#define SHB(src, dst) {                                              \
    gld16((src) + soff,                   (char*)(dst) + t * 16);    \
    gld16((src) + soff + (size_t)64 * K,  (char*)(dst) + t * 16 + 8192); }

#define READ_A(P, m0) {                                                               \
    af[0][0] = *(const s8v*)((const char*)(P) + SWOFF((m0) * 16 + mrow,      quad));      \
    af[0][1] = *(const s8v*)((const char*)(P) + SWOFF((m0) * 16 + mrow,      4 + quad));  \
    af[1][0] = *(const s8v*)((const char*)(P) + SWOFF((m0) * 16 + 16 + mrow, quad));      \
    af[1][1] = *(const s8v*)((const char*)(P) + SWOFF((m0) * 16 + 16 + mrow, 4 + quad)); }

#define READ_B(P) {                                                                   \
    bfr[0][0] = *(const s8v*)((const char*)(P) + SWOFF(bl + mrow,      quad));            \
    bfr[0][1] = *(const s8v*)((const char*)(P) + SWOFF(bl + mrow,      4 + quad));        \
    bfr[1][0] = *(const s8v*)((const char*)(P) + SWOFF(bl + 16 + mrow, quad));            \
    bfr[1][1] = *(const s8v*)((const char*)(P) + SWOFF(bl + 16 + mrow, 4 + quad));        \
    bfr[2][0] = *(const s8v*)((const char*)(P) + SWOFF(bl + 32 + mrow, quad));            \
    bfr[2][1] = *(const s8v*)((const char*)(P) + SWOFF(bl + 32 + mrow, 4 + quad));        \
    bfr[3][0] = *(const s8v*)((const char*)(P) + SWOFF(bl + 48 + mrow, quad));            \
    bfr[3][1] = *(const s8v*)((const char*)(P) + SWOFF(bl + 48 + mrow, 4 + quad)); }

#define MMA8(m0, s) {                                              \
    acc[m0][0]       = MF(af[0][s], bfr[0][s], acc[m0][0]);        \
    acc[m0][1]       = MF(af[0][s], bfr[1][s], acc[m0][1]);        \
    acc[m0][2]       = MF(af[0][s], bfr[2][s], acc[m0][2]);        \
    acc[m0][3]       = MF(af[0][s], bfr[3][s], acc[m0][3]);        \
    acc[(m0) + 1][0] = MF(af[1][s], bfr[0][s], acc[(m0) + 1][0]);  \
    acc[(m0) + 1][1] = MF(af[1][s], bfr[1][s], acc[(m0) + 1][1]);  \
    acc[(m0) + 1][2] = MF(af[1][s], bfr[2][s], acc[(m0) + 1][2]);  \
    acc[(m0) + 1][3] = MF(af[1][s], bfr[3][s], acc[(m0) + 1][3]); }

#define MMA16(m0) { __builtin_amdgcn_s_setprio(1); MMA8(m0, 0) MMA8(m0, 1) \
                    __builtin_amdgcn_s_setprio(0); }

// per-XCD barrier: 32 blocks. Device-scope atomicAdd (agent-coherent by
// default, m20); relaxed agent spin load (NO acquire -> no buffer_inv).
// Data visibility is same-XCD L2: stores drained by __syncthreads (vmcnt 0).
__device__ __forceinline__ void xcd_bar(int* bar, int xcd, int ph) {
    __syncthreads();
    if (threadIdx.x == 0) {
        int* c = bar + xcd * 5 + ph;
        atomicAdd(c, 1);
        int guard = 0;
        while (__hip_atomic_load(c, __ATOMIC_RELAXED, __HIP_MEMORY_SCOPE_AGENT) < 32
               && ++guard < (1 << 26))
            __builtin_amdgcn_s_sleep(2);
    }
    __syncthreads();
}

__global__ __launch_bounds__(512, 2) void deepfm_mega(
    const float* __restrict__ x,  const float* __restrict__ bs,
    const float* __restrict__ bo, float* __restrict__ out,
    unsigned short* __restrict__ xb, unsigned short* __restrict__ h0,
    unsigned short* __restrict__ h1, const unsigned short* __restrict__ wb,
    float* __restrict__ rsm, int* __restrict__ cnt)
{
    constexpr int K = DDIM, N = DDIM;
    __shared__ unsigned short smem[2][2][2][128 * 64];   // 128 KiB
    __shared__ int s_T;

    const int t = threadIdx.x;            // 0..511
    const int lane = t & 63;
    const int wid  = t >> 6;              // 0..7
    const int wr   = wid >> 2;
    const int wc   = wid & 3;
    const int mrow = lane & 15;
    const int quad = lane >> 4;

    // ---- XCD-local tile assignment: T = xcd*32 + slot --------------------
    if (t == 0) {
        unsigned xcc;
        asm volatile("s_getreg_b32 %0, hwreg(HW_REG_XCC_ID)" : "=s"(xcc));
        const int xcd_ = (int)(xcc & 7);
        const int slot = atomicAdd(&cnt[xcd_], 1);
        s_T = xcd_ * 32 + slot;
    }
    __syncthreads();
    const int T = s_T;
    const int xcd = T >> 5;
    const int rowBase = (T >> 2) * 256;   // bx in [xcd*8, xcd*8+8)
    const int colBase = (T & 3) * 256;
    int* const bar = cnt + 8;

    // ---- phase 0: x -> bf16 + rowsum for OUR 64-row slice (XCD-local) ----
    {
        const int rbase = T * 64;
        #pragma unroll 1
        for (int g = 0; g < 8; ++g) {
            const int row = rbase + g * 8 + wid;       // one wave per row
            const float* xr = x + (size_t)row * DDIM;
            float s = 0.f;
            #pragma unroll
            for (int j = 0; j < 4; ++j) {
                const float4 v = *(const float4*)(xr + (j * 64 + lane) * 4);
                ushort4 o;
                o.x = f2bf(v.x); o.y = f2bf(v.y); o.z = f2bf(v.z); o.w = f2bf(v.w);
                *(ushort4*)(xb + (size_t)row * DDIM + (j * 64 + lane) * 4) = o;
                s += v.x + v.y + v.z + v.w;
            }
            #pragma unroll
            for (int off = 32; off > 0; off >>= 1) s += __shfl_down(s, off, 64);
            if (lane == 0) rsm[row] = s;
        }
    }
    xcd_bar(bar, xcd, 0);

    // staging: thread t covers row t>>3 (+64 for 2nd load), 16B chunk t&7.
    const int srow = t >> 3;
    const size_t soff = (size_t)srow * K + (size_t)(((t & 7) ^ (srow & 7)) * 8);

    unsigned short* const a00 = &smem[0][0][0][0];
    unsigned short* const a01 = &smem[0][0][1][0];
    unsigned short* const a10 = &smem[0][1][0][0];
    unsigned short* const a11 = &smem[0][1][1][0];
    unsigned short* const b00 = &smem[1][0][0][0];
    unsigned short* const b01 = &smem[1][0][1][0];
    unsigned short* const b10 = &smem[1][1][0][0];
    unsigned short* const b11 = &smem[1][1][1][0];

    const unsigned short* const aR0 = wr ? a01 : a00;
    const unsigned short* const aR1 = wr ? a11 : a10;
    const unsigned short* const bR0 = (wc >> 1) ? b01 : b00;
    const unsigned short* const bR1 = (wc >> 1) ? b11 : b10;
    const int bl = (wc & 1) * 64;

    // ================= 5 GEMM layers, XCD-synced ==========================
    #pragma unroll 1
    for (int l = 0; l < 5; ++l) {
        const unsigned short* Acur = (l == 0) ? xb : ((l & 1) ? h0 : h1);
        const unsigned short* Bwc  = wb + (size_t)l * DDIM * DDIM;
        const float* bias = (l == 4) ? bo : (bs + (size_t)l * DDIM);
        unsigned short* outb = (l & 1) ? h1 : h0;       // used for l < 4

        const unsigned short* const Ab0 = Acur + (size_t)rowBase * K;
        const unsigned short* const Ab1 = Ab0 + (size_t)128 * K;
        const unsigned short* const Bb0 = Bwc + (size_t)colBase * K;
        const unsigned short* const Bb1 = Bb0 + (size_t)128 * K;

        f4v acc[8][4] = {};
        s8v af[2][2], bfr[4][2];

        // ---- prologue: buf0 A+B, buf1 B; wait buf0, let buf1-B fly -------
        SHA(Ab0,      a00); SHA(Ab1,      a01);
        SHB(Bb0,      b00); SHB(Bb1,      b01);
        SHB(Bb0 + 64, b10); SHB(Bb1 + 64, b11);
        VMC(4);
        BAR();
        READ_B(bR0); READ_A(aR0, 0);          // ph1 frags

        #pragma unroll 1
        for (int it = 0; it < NIT; ++it) {
            const int ka = it * 128, kb = ka + 64;
            const bool more = it < NIT - 1;

            // ======== tile a = 2it (buf0), phases 1-4 ========
            SHA(Ab0 + kb, a10);
            BAR(); MMA16(0); BAR();
            READ_A(aR0, 2);
            SHA(Ab1 + kb, a11);
            BAR(); MMA16(2); BAR();
            READ_A(aR0, 4);
            if (more) SHB(Bb0 + ka + 128, b00);
            BAR(); MMA16(4); BAR();
            READ_A(aR0, 6);
            if (more) SHB(Bb1 + ka + 128, b01);
            if (more) { VMC(4); } else { VMC(0); }
            BAR();
            MMA16(6);
            READ_B(bR1); READ_A(aR1, 0);      // hoisted ph5 frags
            BAR();

            // ======== tile b = 2it+1 (buf1), phases 5-8 ========
            if (more) SHA(Ab0 + ka + 128, a00);
            BAR(); MMA16(0); BAR();
            READ_A(aR1, 2);
            if (more) SHA(Ab1 + ka + 128, a01);
            BAR(); MMA16(2); BAR();
            READ_A(aR1, 4);
            if (more) SHB(Bb0 + kb + 128, b10);
            BAR(); MMA16(4); BAR();
            READ_A(aR1, 6);
            if (more) SHB(Bb1 + kb + 128, b11);
            if (more) { VMC(4); }
            BAR();
            MMA16(6);
            if (more) { READ_B(bR0); READ_A(aR0, 0); }   // next-iter ph1
            BAR();
        }

        // ---- epilogue. C/D layout: col = lane&15, row = quad*4 + reg -----
        if (l == 4) {
            float* sCf = (float*)smem;                 // 128x256 fp32
            #pragma unroll 1
            for (int half = 0; half < 2; ++half) {
                __syncthreads();
                if (wr == half) {
                    #pragma unroll
                    for (int ni = 0; ni < 4; ++ni) {
                        const int n = wc * 64 + ni * 16 + mrow;
                        const float bv = bias[colBase + n];
                        #pragma unroll
                        for (int mi = 0; mi < 8; ++mi)
                            #pragma unroll
                            for (int r = 0; r < 4; ++r)
                                sCf[(mi * 16 + quad * 4 + r) * 256 + n] = acc[mi][ni][r] + bv;
                    }
                }
                __syncthreads();
                #pragma unroll
                for (int p = 0; p < 16; ++p) {
                    const int idx = t + p * 512;       // float4 chunk 0..8191
                    const int row = idx >> 6, ch = idx & 63;
                    const float4 v = ((const float4*)sCf)[idx];
                    *(float4*)(out + (size_t)(rowBase + half * 128 + row) * N + colBase + ch * 4) = v;
                }
            }
        } else {
            __syncthreads();
            unsigned short* sC = (unsigned short*)smem;  // 256x256 bf16
            #pragma unroll
            for (int ni = 0; ni < 4; ++ni) {
                const int n = wc * 64 + ni * 16 + mrow;
                const float bv = bias[colBase + n];
                #pragma unroll
                for (int mi = 0; mi < 8; ++mi)
                    #pragma unroll
                    for (int r = 0; r < 4; ++r) {
                        const int row = wr * 128 + mi * 16 + quad * 4 + r;
                        float v = acc[mi][ni][r] + bv;
                        v = v > 0.f ? v : 0.f;
                        sC[row * 256 + n] = f2bf(v);
                    }
            }
            __syncthreads();
            #pragma unroll
            for (int p = 0; p < 16; ++p) {
                const int idx = t + p * 512;             // ushort8 chunk
                const int row = idx >> 5, ch = idx & 31;
                s8v c = *(const s8v*)&sC[row * 256 + ch * 8];
                if (l == 3) {
                    const float rsv = rsm[rowBase + row];
                    const s8v xv = *(const s8v*)&xb[(size_t)(rowBase + row) * DDIM + colBase + ch * 8];
                    #pragma unroll
                    for (int j = 0; j < 8; ++j) {
                        float itv = bf2f((unsigned short)xv[j]) * rsv;
                        itv = itv > 0.f ? itv : 0.f;
                        c[j] = (short)f2bf(0.5f * (bf2f((unsigned short)c[j]) + itv));
                    }
                }
                *(s8v*)&outb[(size_t)(rowBase + row) * DDIM + colBase + ch * 8] = c;
            }
        }

        if (l < 4) xcd_bar(bar, xcd, l + 1);
    }
}

extern "C" void kernel_launch(void* const* d_in, const int* in_sizes, int n_in,
                              void* d_out, int out_size, void* d_ws, size_t ws_size,
                              hipStream_t stream) {
    const float* x  = (const float*)d_in[0];
    const float* Ws = (const float*)d_in[1];
    const float* bs = (const float*)d_in[2];
    const float* Wo = (const float*)d_in[3];
    const float* bo = (const float*)d_in[4];
    float* out = (float*)d_out;

    char* ws = (char*)d_ws;
    unsigned short* xb  = (unsigned short*)(ws);                 // 32 MB bf16 x
    unsigned short* h0  = (unsigned short*)(ws + 33554432);      // 32 MB
    unsigned short* h1  = (unsigned short*)(ws + 67108864);      // 32 MB
    unsigned short* wb  = (unsigned short*)(ws + 100663296);     // 10 MB weights bf16
    float*          rsm = (float*)(ws + 111149056);              // 64 KB rowsum

    // counters (8 slot + 8x5 barrier = 192 B): tail of ws if it fits, else
    // tail of out (zeroed by memset, overwritten by layer-4 stores later).
    int* cnt = (ws_size >= 111214592 + 256)
                   ? (int*)(ws + 111214592)
                   : (int*)((char*)d_out + 67108864 - 256);

    hipMemsetAsync(cnt, 0, 192, stream);
    prep_w<<<1280, 256, 0, stream>>>(Ws, Wo, wb);

    void* args[10] = {(void*)&x, (void*)&bs, (void*)&bo, (void*)&out,
                      (void*)&xb, (void*)&h0, (void*)&h1, (void*)&wb,
                      (void*)&rsm, (void*)&cnt};
    hipLaunchCooperativeKernel(deepfm_mega, dim3(256), dim3(512), args, 0u, stream);
}

// Round 6
// 382.310 us; speedup vs baseline: 2.4150x; 1.0860x over previous
//
#include <hip/hip_runtime.h>

// DeepFM: B=16384, D=1024, L=4.
// Round 6: XCD-local fused GEMM chain, REGULAR launch (round-5 showed the
// cooperative launch API itself costs ~115us; co-residency is guaranteed
// structurally: 128KiB LDS + launch_bounds(512,2) => 1 block/CU, grid=256=
// #CUs, stream-ordered so no competing kernels). x-prep moved back to the
// high-parallelism prep dispatch (mega's 1-block/CU phase-0 was ~30us vs
// 22us standalone). XCD-local dataflow + per-XCD barrier proven in round 5:
//   block T = xcd*32 + slot owns tile (bx=T>>2, by=T&3); all h producer/
//   consumer edges stay in one XCD's L2; SC0 (L1-bypass) on A staging kills
//   L1 staleness; barrier = device atomicAdd + relaxed agent spin (no cache
//   maintenance ops).

#define DDIM 1024
#define BROWS 16384
#define NIT 8   // K / 128

typedef __attribute__((ext_vector_type(8))) short s8v;   // 8 bf16
typedef __attribute__((ext_vector_type(4))) float f4v;   // 4 fp32

__device__ __forceinline__ unsigned short f2bf(float f) {
    unsigned int u = __float_as_uint(f);
    u += 0x7fffu + ((u >> 16) & 1u);   // round-to-nearest-even
    return (unsigned short)(u >> 16);
}
__device__ __forceinline__ float bf2f(unsigned short u) {
    return __uint_as_float(((unsigned int)u) << 16);
}
__device__ __forceinline__ void gld16(const void* g, void* l) {
    __builtin_amdgcn_global_load_lds(
        (const __attribute__((address_space(1))) unsigned int*)g,
        (__attribute__((address_space(3))) unsigned int*)l, 16, 0, 0);
}
// SC0 (CPol bit0): agent-coherent load, bypasses L1 -> no stale h lines.
__device__ __forceinline__ void gld16c(const void* g, void* l) {
    __builtin_amdgcn_global_load_lds(
        (const __attribute__((address_space(1))) unsigned int*)g,
        (__attribute__((address_space(3))) unsigned int*)l, 16, 0, 1);
}

// -------- fused prep: blocks [0,16384) x rows; [16384, 17664) weights ----
__global__ __launch_bounds__(256) void prep_cvt_kernel(
    const float* __restrict__ x,  const float* __restrict__ Ws,
    const float* __restrict__ Wo, unsigned short* __restrict__ xb,
    unsigned short* __restrict__ wb, float* __restrict__ rowsum)
{
    const int t = threadIdx.x;
    if (blockIdx.x < BROWS) {
        const int row = blockIdx.x;
        const float4 v = *(const float4*)(x + (size_t)row * DDIM + t * 4);
        ushort4 o;
        o.x = f2bf(v.x); o.y = f2bf(v.y); o.z = f2bf(v.z); o.w = f2bf(v.w);
        *(ushort4*)(xb + (size_t)row * DDIM + t * 4) = o;
        float s = v.x + v.y + v.z + v.w;
        #pragma unroll
        for (int off = 32; off > 0; off >>= 1) s += __shfl_down(s, off, 64);
        __shared__ float red[4];
        const int wave = t >> 6, lane = t & 63;
        if (lane == 0) red[wave] = s;
        __syncthreads();
        if (t == 0) rowsum[row] = red[0] + red[1] + red[2] + red[3];
    } else {
        const int base = (blockIdx.x - BROWS) * 1024;
        #pragma unroll
        for (int j = 0; j < 4; ++j) {
            const int idx = base + j * 256 + t;
            const float4 v = (idx < 4 * 262144) ? ((const float4*)Ws)[idx]
                                                : ((const float4*)Wo)[idx - 4 * 262144];
            ushort4 o;
            o.x = f2bf(v.x); o.y = f2bf(v.y); o.z = f2bf(v.z); o.w = f2bf(v.w);
            ((ushort4*)wb)[idx] = o;
        }
    }
}

#define MF(a, b, c) __builtin_amdgcn_mfma_f32_16x16x32_bf16(a, b, c, 0, 0, 0)
#define BAR()   __builtin_amdgcn_s_barrier()
#define VMC(n)  asm volatile("s_waitcnt vmcnt(" #n ")" ::: "memory")

// byte offset within one 128x64-bf16 half-tile, with 16B-chunk XOR swizzle
#define SWOFF(lr, cc) ((lr) * 128 + ((((cc) ^ ((lr) & 7))) << 4))

#define SHA(src, dst) {                                              \
    gld16c((src) + soff,                   (char*)(dst) + t * 16);   \
    gld16c((src) + soff + (size_t)64 * K,  (char*)(dst) + t * 16 + 8192); }
#define SHB(src, dst) {                                              \
    gld16((src) + soff,                   (char*)(dst) + t * 16);    \
    gld16((src) + soff + (size_t)64 * K,  (char*)(dst) + t * 16 + 8192); }

#define READ_A(P, m0) {                                                               \
    af[0][0] = *(const s8v*)((const char*)(P) + SWOFF((m0) * 16 + mrow,      quad));      \
    af[0][1] = *(const s8v*)((const char*)(P) + SWOFF((m0) * 16 + mrow,      4 + quad));  \
    af[1][0] = *(const s8v*)((const char*)(P) + SWOFF((m0) * 16 + 16 + mrow, quad));      \
    af[1][1] = *(const s8v*)((const char*)(P) + SWOFF((m0) * 16 + 16 + mrow, 4 + quad)); }

#define READ_B(P) {                                                                   \
    bfr[0][0] = *(const s8v*)((const char*)(P) + SWOFF(bl + mrow,      quad));            \
    bfr[0][1] = *(const s8v*)((const char*)(P) + SWOFF(bl + mrow,      4 + quad));        \
    bfr[1][0] = *(const s8v*)((const char*)(P) + SWOFF(bl + 16 + mrow, quad));            \
    bfr[1][1] = *(const s8v*)((const char*)(P) + SWOFF(bl + 16 + mrow, 4 + quad));        \
    bfr[2][0] = *(const s8v*)((const char*)(P) + SWOFF(bl + 32 + mrow, quad));            \
    bfr[2][1] = *(const s8v*)((const char*)(P) + SWOFF(bl + 32 + mrow, 4 + quad));        \
    bfr[3][0] = *(const s8v*)((const char*)(P) + SWOFF(bl + 48 + mrow, quad));            \
    bfr[3][1] = *(const s8v*)((const char*)(P) + SWOFF(bl + 48 + mrow, 4 + quad)); }

#define MMA8(m0, s) {                                              \
    acc[m0][0]       = MF(af[0][s], bfr[0][s], acc[m0][0]);        \
    acc[m0][1]       = MF(af[0][s], bfr[1][s], acc[m0][1]);        \
    acc[m0][2]       = MF(af[0][s], bfr[2][s], acc[m0][2]);        \
    acc[m0][3]       = MF(af[0][s], bfr[3][s], acc[m0][3]);        \
    acc[(m0) + 1][0] = MF(af[1][s], bfr[0][s], acc[(m0) + 1][0]);  \
    acc[(m0) + 1][1] = MF(af[1][s], bfr[1][s], acc[(m0) + 1][1]);  \
    acc[(m0) + 1][2] = MF(af[1][s], bfr[2][s], acc[(m0) + 1][2]);  \
    acc[(m0) + 1][3] = MF(af[1][s], bfr[3][s], acc[(m0) + 1][3]); }

#define MMA16(m0) { __builtin_amdgcn_s_setprio(1); MMA8(m0, 0) MMA8(m0, 1) \
                    __builtin_amdgcn_s_setprio(0); }

// per-XCD barrier: 32 blocks. Device-scope atomicAdd; relaxed agent spin
// (no cache maintenance). Data visibility is same-XCD L2 (stores drained
// by __syncthreads' vmcnt(0)). Guard: degrade to wrong-answer, not hang.
__device__ __forceinline__ void xcd_bar(int* bar, int xcd, int ph) {
    __syncthreads();
    if (threadIdx.x == 0) {
        int* c = bar + xcd * 5 + ph;
        atomicAdd(c, 1);
        int guard = 0;
        while (__hip_atomic_load(c, __ATOMIC_RELAXED, __HIP_MEMORY_SCOPE_AGENT) < 32
               && ++guard < (1 << 22))
            __builtin_amdgcn_s_sleep(2);
    }
    __syncthreads();
}

__global__ __launch_bounds__(512, 2) void deepfm_mega(
    const float* __restrict__ bs, const float* __restrict__ bo,
    float* __restrict__ out,
    const unsigned short* __restrict__ xb, unsigned short* __restrict__ h0,
    unsigned short* __restrict__ h1, const unsigned short* __restrict__ wb,
    const float* __restrict__ rsm, int* __restrict__ cnt)
{
    constexpr int K = DDIM, N = DDIM;
    __shared__ unsigned short smem[2][2][2][128 * 64];   // 128 KiB
    __shared__ int s_T;

    const int t = threadIdx.x;            // 0..511
    const int lane = t & 63;
    const int wid  = t >> 6;              // 0..7
    const int wr   = wid >> 2;
    const int wc   = wid & 3;
    const int mrow = lane & 15;
    const int quad = lane >> 4;

    // ---- XCD-local tile assignment: T = xcd*32 + slot --------------------
    if (t == 0) {
        unsigned xcc;
        asm volatile("s_getreg_b32 %0, hwreg(HW_REG_XCC_ID)" : "=s"(xcc));
        const int xcd_ = (int)(xcc & 7);
        const int slot = atomicAdd(&cnt[xcd_], 1);
        s_T = xcd_ * 32 + slot;
    }
    __syncthreads();
    const int T = s_T;
    const int xcd = T >> 5;
    const int rowBase = (T >> 2) * 256;   // row panel: 4 sibling blocks/XCD
    const int colBase = (T & 3) * 256;
    int* const bar = cnt + 8;

    // staging: thread t covers row t>>3 (+64 for 2nd load), 16B chunk t&7.
    const int srow = t >> 3;
    const size_t soff = (size_t)srow * K + (size_t)(((t & 7) ^ (srow & 7)) * 8);

    unsigned short* const a00 = &smem[0][0][0][0];
    unsigned short* const a01 = &smem[0][0][1][0];
    unsigned short* const a10 = &smem[0][1][0][0];
    unsigned short* const a11 = &smem[0][1][1][0];
    unsigned short* const b00 = &smem[1][0][0][0];
    unsigned short* const b01 = &smem[1][0][1][0];
    unsigned short* const b10 = &smem[1][1][0][0];
    unsigned short* const b11 = &smem[1][1][1][0];

    const unsigned short* const aR0 = wr ? a01 : a00;
    const unsigned short* const aR1 = wr ? a11 : a10;
    const unsigned short* const bR0 = (wc >> 1) ? b01 : b00;
    const unsigned short* const bR1 = (wc >> 1) ? b11 : b10;
    const int bl = (wc & 1) * 64;

    // ================= 5 GEMM layers, XCD-synced ==========================
    #pragma unroll 1
    for (int l = 0; l < 5; ++l) {
        const unsigned short* Acur = (l == 0) ? xb : ((l & 1) ? h0 : h1);
        const unsigned short* Bwc  = wb + (size_t)l * DDIM * DDIM;
        const float* bias = (l == 4) ? bo : (bs + (size_t)l * DDIM);
        unsigned short* outb = (l & 1) ? h1 : h0;       // used for l < 4

        const unsigned short* const Ab0 = Acur + (size_t)rowBase * K;
        const unsigned short* const Ab1 = Ab0 + (size_t)128 * K;
        const unsigned short* const Bb0 = Bwc + (size_t)colBase * K;
        const unsigned short* const Bb1 = Bb0 + (size_t)128 * K;

        f4v acc[8][4] = {};
        s8v af[2][2], bfr[4][2];

        // ---- prologue: buf0 A+B, buf1 B; wait buf0, let buf1-B fly -------
        SHA(Ab0,      a00); SHA(Ab1,      a01);
        SHB(Bb0,      b00); SHB(Bb1,      b01);
        SHB(Bb0 + 64, b10); SHB(Bb1 + 64, b11);
        VMC(4);
        BAR();
        READ_B(bR0); READ_A(aR0, 0);          // ph1 frags

        #pragma unroll 1
        for (int it = 0; it < NIT; ++it) {
            const int ka = it * 128, kb = ka + 64;
            const bool more = it < NIT - 1;

            // ======== tile a = 2it (buf0), phases 1-4 ========
            SHA(Ab0 + kb, a10);
            BAR(); MMA16(0); BAR();
            READ_A(aR0, 2);
            SHA(Ab1 + kb, a11);
            BAR(); MMA16(2); BAR();
            READ_A(aR0, 4);
            if (more) SHB(Bb0 + ka + 128, b00);
            BAR(); MMA16(4); BAR();
            READ_A(aR0, 6);
            if (more) SHB(Bb1 + ka + 128, b01);
            if (more) { VMC(4); } else { VMC(0); }
            BAR();
            MMA16(6);
            READ_B(bR1); READ_A(aR1, 0);      // hoisted ph5 frags
            BAR();

            // ======== tile b = 2it+1 (buf1), phases 5-8 ========
            if (more) SHA(Ab0 + ka + 128, a00);
            BAR(); MMA16(0); BAR();
            READ_A(aR1, 2);
            if (more) SHA(Ab1 + ka + 128, a01);
            BAR(); MMA16(2); BAR();
            READ_A(aR1, 4);
            if (more) SHB(Bb0 + kb + 128, b10);
            BAR(); MMA16(4); BAR();
            READ_A(aR1, 6);
            if (more) SHB(Bb1 + kb + 128, b11);
            if (more) { VMC(4); }
            BAR();
            MMA16(6);
            if (more) { READ_B(bR0); READ_A(aR0, 0); }   // next-iter ph1
            BAR();
        }

        // ---- epilogue. C/D layout: col = lane&15, row = quad*4 + reg -----
        if (l == 4) {
            float* sCf = (float*)smem;                 // 128x256 fp32
            #pragma unroll 1
            for (int half = 0; half < 2; ++half) {
                __syncthreads();
                if (wr == half) {
                    #pragma unroll
                    for (int ni = 0; ni < 4; ++ni) {
                        const int n = wc * 64 + ni * 16 + mrow;
                        const float bv = bias[colBase + n];
                        #pragma unroll
                        for (int mi = 0; mi < 8; ++mi)
                            #pragma unroll
                            for (int r = 0; r < 4; ++r)
                                sCf[(mi * 16 + quad * 4 + r) * 256 + n] = acc[mi][ni][r] + bv;
                    }
                }
                __syncthreads();
                #pragma unroll
                for (int p = 0; p < 16; ++p) {
                    const int idx = t + p * 512;       // float4 chunk 0..8191
                    const int row = idx >> 6, ch = idx & 63;
                    const float4 v = ((const float4*)sCf)[idx];
                    *(float4*)(out + (size_t)(rowBase + half * 128 + row) * N + colBase + ch * 4) = v;
                }
            }
        } else {
            __syncthreads();
            unsigned short* sC = (unsigned short*)smem;  // 256x256 bf16
            #pragma unroll
            for (int ni = 0; ni < 4; ++ni) {
                const int n = wc * 64 + ni * 16 + mrow;
                const float bv = bias[colBase + n];
                #pragma unroll
                for (int mi = 0; mi < 8; ++mi)
                    #pragma unroll
                    for (int r = 0; r < 4; ++r) {
                        const int row = wr * 128 + mi * 16 + quad * 4 + r;
                        float v = acc[mi][ni][r] + bv;
                        v = v > 0.f ? v : 0.f;
                        sC[row * 256 + n] = f2bf(v);
                    }
            }
            __syncthreads();
            #pragma unroll
            for (int p = 0; p < 16; ++p) {
                const int idx = t + p * 512;             // ushort8 chunk
                const int row = idx >> 5, ch = idx & 31;
                s8v c = *(const s8v*)&sC[row * 256 + ch * 8];
                if (l == 3) {
                    const float rsv = rsm[rowBase + row];
                    const s8v xv = *(const s8v*)&xb[(size_t)(rowBase + row) * DDIM + colBase + ch * 8];
                    #pragma unroll
                    for (int j = 0; j < 8; ++j) {
                        float itv = bf2f((unsigned short)xv[j]) * rsv;
                        itv = itv > 0.f ? itv : 0.f;
                        c[j] = (short)f2bf(0.5f * (bf2f((unsigned short)c[j]) + itv));
                    }
                }
                *(s8v*)&outb[(size_t)(rowBase + row) * DDIM + colBase + ch * 8] = c;
            }
        }

        if (l < 4) xcd_bar(bar, xcd, l);
    }
}

extern "C" void kernel_launch(void* const* d_in, const int* in_sizes, int n_in,
                              void* d_out, int out_size, void* d_ws, size_t ws_size,
                              hipStream_t stream) {
    const float* x  = (const float*)d_in[0];
    const float* Ws = (const float*)d_in[1];
    const float* bs = (const float*)d_in[2];
    const float* Wo = (const float*)d_in[3];
    const float* bo = (const float*)d_in[4];
    float* out = (float*)d_out;

    char* ws = (char*)d_ws;
    unsigned short* xb  = (unsigned short*)(ws);                 // 32 MB bf16 x
    unsigned short* h0  = (unsigned short*)(ws + 33554432);      // 32 MB
    unsigned short* h1  = (unsigned short*)(ws + 67108864);      // 32 MB
    unsigned short* wb  = (unsigned short*)(ws + 100663296);     // 10 MB weights bf16
    float*          rsm = (float*)(ws + 111149056);              // 64 KB rowsum

    // counters (8 slot + 8x5 barrier = 192 B): tail of ws if it fits, else
    // tail of out (zeroed here, overwritten by layer-4 stores afterwards).
    int* cnt = (ws_size >= 111214592 + 256)
                   ? (int*)(ws + 111214592)
                   : (int*)((char*)d_out + 67108864 - 256);

    hipMemsetAsync(cnt, 0, 192, stream);
    prep_cvt_kernel<<<BROWS + 1280, 256, 0, stream>>>(x, Ws, Wo, xb, wb, rsm);
    deepfm_mega<<<dim3(256), dim3(512), 0, stream>>>(bs, bo, out, xb, h0, h1,
                                                     wb, rsm, cnt);
}